// Round 1
// baseline (369.649 us; speedup 1.0000x reference)
//
#include <hip/hip_runtime.h>

// Embedding gather: out[i, :] = table[indices[i], :]
// VOCAB = 1,000,000 rows, EMBED_DIM = 16 floats (64 B) per row,
// NUM_INDICES = 4,194,304.
//
// Layout strategy: one thread per float4 (16 B) of output -> 4 threads/row.
// Consecutive lanes write consecutive float4s => fully coalesced 1 KB/wave
// stores. The 4 lanes of a row read the same index (same-address broadcast)
// and a contiguous 64 B table row. Table (64 MB) fits in the 256 MB L3, so
// the random gather is largely cache-served; the kernel is bound by the
// 256 MB output write stream.

__global__ void __launch_bounds__(256)
embed_gather_kernel(const int* __restrict__ indices,
                    const float4* __restrict__ table4,
                    float4* __restrict__ out4,
                    int n_rows) {
    int t = blockIdx.x * blockDim.x + threadIdx.x;
    int row = t >> 2;   // which index
    int seg = t & 3;    // which float4 within the 16-float row
    if (row < n_rows) {
        int r = indices[row];
        out4[t] = table4[(size_t)r * 4 + seg];
    }
}

extern "C" void kernel_launch(void* const* d_in, const int* in_sizes, int n_in,
                              void* d_out, int out_size, void* d_ws, size_t ws_size,
                              hipStream_t stream) {
    const int*    indices = (const int*)d_in[0];
    const float4* table4  = (const float4*)d_in[1];
    float4*       out4    = (float4*)d_out;

    int n_rows = in_sizes[0];          // 4,194,304
    long long total_threads = (long long)n_rows * 4;  // one float4 each
    int block = 256;
    int grid = (int)((total_threads + block - 1) / block);

    embed_gather_kernel<<<grid, block, 0, stream>>>(indices, table4, out4, n_rows);
}